// Round 10
// baseline (2708.648 us; speedup 1.0000x reference)
//
#include <hip/hip_runtime.h>

// GNN node embedding (GINEConv x5), fp32, MI355X gfx950.
// N=50000 nodes, E=800000 edges, D=64, X_DIM=92, EA_DIM=50, L=5.
//
// R9 = R8 resubmission (R6/R7/R8 benches all died on infra; design from R6
// has never been measured). Changes vs the last MEASURED kernel (R5):
//  - k_edge: lane=d, wc[50] in VGPRs, ea rows via uniform-address VECTOR loads
//    (asm-blinded zero VGPR offset -> global_load broadcast, not s_load);
//    float2 loads (200B rows are 8B-aligned); metadata per-lane + readlane;
//    run-length atomic flush kept.  [R5: VALUBusy 40%, SMEM-latency-bound]
//  - k_mlp: wave-per-output-quarter, lane=node, grid 782 blocks (12 waves/CU),
//    LDS y-exchange between the two GEMVs.  [R5: 196 blocks = 0.77 waves/SIMD]

#define NN 50000
#define NE 800000
#define D 64
#define NL 5
#define XD 92
#define EAD 50
#define BN_EPS 1e-5f
#define NBLK ((NN + 255) / 256)   // 196 scan blocks
#define TILE_E 256                // edges per block (64 per wave), NE = 3125*256
#define MLPB ((NN + 63) / 64)     // 782 k_mlp blocks

// ---------------- prep: transpose weights ----------------
__global__ void k_prep(const float* __restrict__ atomW, const float* __restrict__ W1,
                       const float* __restrict__ W2, float* __restrict__ atomWt,
                       float* __restrict__ W1t, float* __restrict__ W2t) {
  int tid = blockIdx.x * blockDim.x + threadIdx.x;
  int nt = gridDim.x * blockDim.x;
  for (int i = tid; i < XD * D; i += nt) {
    int k = i / D, d = i % D;
    atomWt[d * XD + k] = atomW[i];
  }
  for (int i = tid; i < NL * D * D; i += nt) {
    int l = i / (D * D), r = i % (D * D);
    int k = r / D, d = r % D;
    W1t[(l * D + d) * D + k] = W1[i];
    W2t[(l * D + d) * D + k] = W2[i];
  }
}

// ---------------- atom encoder: h = x @ atom_W + b ----------------
// lane = node; x row in VGPRs; transposed-W rows via uniform s_loads.
__global__ __launch_bounds__(256) void k_atom(const float* __restrict__ x,
    const float* __restrict__ Wt, const float* __restrict__ b,
    float* __restrict__ h) {
  int n = blockIdx.x * blockDim.x + threadIdx.x;
  if (n >= NN) return;
  const float* xp = x + (size_t)n * XD;
  float xr[XD];
#pragma unroll
  for (int k = 0; k < XD; k += 4) {
    float4 v = *reinterpret_cast<const float4*>(xp + k);
    xr[k] = v.x; xr[k + 1] = v.y; xr[k + 2] = v.z; xr[k + 3] = v.w;
  }
  float hr[D];
#pragma unroll
  for (int d = 0; d < D; ++d) {
    const float* wr = Wt + d * XD;  // uniform -> s_loads
    float a0 = 0.f, a1 = 0.f, a2 = 0.f, a3 = 0.f;
#pragma unroll
    for (int k = 0; k < XD; k += 4) {
      a0 = fmaf(xr[k + 0], wr[k + 0], a0);
      a1 = fmaf(xr[k + 1], wr[k + 1], a1);
      a2 = fmaf(xr[k + 2], wr[k + 2], a2);
      a3 = fmaf(xr[k + 3], wr[k + 3], a3);
    }
    hr[d] = (a0 + a1) + (a2 + a3) + b[d];
  }
  float* hp = h + (size_t)n * D;
#pragma unroll
  for (int d = 0; d < D; d += 4)
    *reinterpret_cast<float4*>(hp + d) = make_float4(hr[d], hr[d+1], hr[d+2], hr[d+3]);
}

// ---------------- CSR build ----------------
__global__ __launch_bounds__(256) void k_deg(const int* __restrict__ ei,
                                             int* __restrict__ deg) {
  int e = blockIdx.x * blockDim.x + threadIdx.x;
  if (e < NE) atomicAdd(&deg[ei[NE + e]], 1);
}

__global__ __launch_bounds__(256) void k_scan_a(const int* __restrict__ deg,
    int* __restrict__ lps, int* __restrict__ bsum) {
  __shared__ int s[256];
  int t = threadIdx.x;
  int i = blockIdx.x * 256 + t;
  int v = (i < NN) ? deg[i] : 0;
  s[t] = v;
  __syncthreads();
#pragma unroll
  for (int off = 1; off < 256; off <<= 1) {
    int xv = (t >= off) ? s[t - off] : 0;
    __syncthreads();
    s[t] += xv;
    __syncthreads();
  }
  if (i < NN) lps[i] = s[t] - v;         // exclusive
  if (t == 255) bsum[blockIdx.x] = s[255];
}

__global__ __launch_bounds__(256) void k_scan_b(const int* __restrict__ bsum,
                                                int* __restrict__ bpre) {
  __shared__ int s[256];
  int t = threadIdx.x;
  int v = (t < NBLK) ? bsum[t] : 0;
  s[t] = v;
  __syncthreads();
#pragma unroll
  for (int off = 1; off < 256; off <<= 1) {
    int xv = (t >= off) ? s[t - off] : 0;
    __syncthreads();
    s[t] += xv;
    __syncthreads();
  }
  bpre[t] = s[t] - v;
}

__global__ __launch_bounds__(256) void k_fill(const int* __restrict__ lps,
    const int* __restrict__ bpre, int* __restrict__ rowptr,
    int* __restrict__ cursor) {
  int i = blockIdx.x * blockDim.x + threadIdx.x;
  if (i < NN) {
    int v = lps[i] + bpre[i >> 8];
    rowptr[i] = v;
    cursor[i] = v;
  }
  if (i == 0) rowptr[NN] = NE;
}

__global__ __launch_bounds__(256) void k_scatter(const int* __restrict__ ei,
    int* __restrict__ cursor, int* __restrict__ esrc, int* __restrict__ eidl,
    int* __restrict__ dstp) {
  int e = blockIdx.x * blockDim.x + threadIdx.x;
  if (e >= NE) return;
  int dst = ei[NE + e];
  int p = atomicAdd(&cursor[dst], 1);
  esrc[p] = ei[e];
  eidl[p] = e;
  dstp[p] = dst;
}

// ---------------- edge kernel: lane = d, vector-broadcast ea ----------------
// Wave owns 64 CSR-ordered edges. wc[50] (weight column for d=lane) in VGPRs.
// Per edge: 25 float2 uniform-address VECTOR loads of the ea row (8B-aligned
// always; zoff blinds the compiler so it can't prove uniformity ->
// global_load, HW broadcasts the single transaction), 50 VALU FMAs, h[src]
// coalesced row load, relu, run-length accumulate; atomic row flush on dst
// change (scalar compare, uniform branch).
__global__ __launch_bounds__(256) void k_edge(const float* __restrict__ h,
    const float* __restrict__ ea, const float* __restrict__ eW,
    const float* __restrict__ eb, const int* __restrict__ esrc,
    const int* __restrict__ eidl, const int* __restrict__ dstp,
    int layer, float* __restrict__ agg) {
  int tid = threadIdx.x;
  int lane = tid & 63;
  int w = tid >> 6;
  int base = blockIdx.x * TILE_E + w * 64;   // this wave's 64 edges

  int veid = eidl[base + lane];   // coalesced per-lane metadata
  int vsrc = esrc[base + lane];
  int vdst = dstp[base + lane];

  const float* Wl = eW + (size_t)layer * EAD * D;  // original [k][d] layout
  float wc[EAD];
#pragma unroll
  for (int k = 0; k < EAD; ++k) wc[k] = Wl[k * D + lane];  // coalesced column
  float bd = eb[layer * D + lane];

  int zoff = 0;
  asm volatile("" : "+v"(zoff));   // opaque zero: forces vector-path ea loads

  float acc = 0.f;
  int cur = __builtin_amdgcn_readlane(vdst, 0);
#pragma unroll 2
  for (int j = 0; j < 64; ++j) {
    int eid = __builtin_amdgcn_readlane(veid, j);  // uniform (SGPR)
    int src = __builtin_amdgcn_readlane(vsrc, j);
    int dst = __builtin_amdgcn_readlane(vdst, j);
    const float* ep = ea + (size_t)eid * EAD + zoff;  // s-base + v-offset(0)
    float2 er[25];                                    // 8B-aligned loads
#pragma unroll
    for (int q = 0; q < 25; ++q)
      er[q] = *reinterpret_cast<const float2*>(ep + 2 * q);
    float hv = h[(size_t)src * D + lane];  // coalesced 256B row
    if (dst != cur) {                       // uniform branch
      unsafeAtomicAdd(&agg[(size_t)cur * D + lane], acc);
      acc = 0.f;
      cur = dst;
    }
    float a0 = 0.f, a1 = 0.f, a2 = 0.f, a3 = 0.f;
#pragma unroll
    for (int q = 0; q < 24; q += 2) {
      a0 = fmaf(er[q].x, wc[2 * q + 0], a0);
      a1 = fmaf(er[q].y, wc[2 * q + 1], a1);
      a2 = fmaf(er[q + 1].x, wc[2 * q + 2], a2);
      a3 = fmaf(er[q + 1].y, wc[2 * q + 3], a3);
    }
    a0 = fmaf(er[24].x, wc[48], a0);
    a1 = fmaf(er[24].y, wc[49], a1);
    float lin = (a0 + a1) + (a2 + a3) + bd;
    acc += fmaxf(hv + lin, 0.f);
  }
  unsafeAtomicAdd(&agg[(size_t)cur * D + lane], acc);
}

// ---------------- node MLP: wave-per-quarter, lane = node ----------------
// Block = 64 nodes x 4 waves; wave w computes outputs d in [w*16, w*16+16).
// z=(1+eps)h+agg per thread (full row, 4x redundant load, L2-hit); GEMM1 ->
// y-quarter -> LDS exchange -> full y row -> GEMM2 -> t-quarter into agg.
// Weight rows wave-uniform s_loads. Grid 782 blocks = 12 waves/CU.
__global__ __launch_bounds__(256) void k_mlp(const float* __restrict__ h,
    const float* __restrict__ W1t, const float* __restrict__ b1,
    const float* __restrict__ W2t, const float* __restrict__ b2,
    const float* __restrict__ eps, int layer, float* __restrict__ agg) {
  __shared__ float ylds[64 * 68];  // 64 nodes x 64 y, stride 68 (17.4 KB)
  int tid = threadIdx.x;
  int lane = tid & 63;
  int w = tid >> 6;
  int n = blockIdx.x * 64 + lane;
  bool act = (n < NN);
  int nc = act ? n : (NN - 1);
  float ope = 1.f + eps[layer];
  const float* hp = h + (size_t)nc * D;
  const float* ap = agg + (size_t)nc * D;
  float zr[D];
#pragma unroll
  for (int k = 0; k < D; k += 4) {
    float4 hv = *reinterpret_cast<const float4*>(hp + k);
    float4 av = *reinterpret_cast<const float4*>(ap + k);
    zr[k]   = fmaf(ope, hv.x, av.x);
    zr[k+1] = fmaf(ope, hv.y, av.y);
    zr[k+2] = fmaf(ope, hv.z, av.z);
    zr[k+3] = fmaf(ope, hv.w, av.w);
  }
  const float* W1l = W1t + (size_t)layer * D * D;
  const float* b1p = b1 + layer * D;
  float y[16];
#pragma unroll
  for (int dd = 0; dd < 16; ++dd) {
    int d = w * 16 + dd;
    const float* wr = W1l + d * D;  // wave-uniform -> s_loads
    float a0 = 0.f, a1 = 0.f, a2 = 0.f, a3 = 0.f;
#pragma unroll
    for (int k = 0; k < D; k += 4) {
      a0 = fmaf(zr[k + 0], wr[k + 0], a0);
      a1 = fmaf(zr[k + 1], wr[k + 1], a1);
      a2 = fmaf(zr[k + 2], wr[k + 2], a2);
      a3 = fmaf(zr[k + 3], wr[k + 3], a3);
    }
    y[dd] = fmaxf((a0 + a1) + (a2 + a3) + b1p[d], 0.f);
  }
  float* yl = &ylds[lane * 68 + w * 16];
#pragma unroll
  for (int q = 0; q < 4; ++q)
    *reinterpret_cast<float4*>(yl + 4 * q) =
        make_float4(y[4*q], y[4*q+1], y[4*q+2], y[4*q+3]);
  __syncthreads();
  float yr[D];
#pragma unroll
  for (int q = 0; q < 16; ++q) {
    float4 v = *reinterpret_cast<const float4*>(&ylds[lane * 68 + 4 * q]);
    yr[4*q] = v.x; yr[4*q+1] = v.y; yr[4*q+2] = v.z; yr[4*q+3] = v.w;
  }
  const float* W2l = W2t + (size_t)layer * D * D;
  const float* b2p = b2 + layer * D;
  float tq[16];
#pragma unroll
  for (int dd = 0; dd < 16; ++dd) {
    int d = w * 16 + dd;
    const float* wr = W2l + d * D;  // wave-uniform -> s_loads
    float a0 = 0.f, a1 = 0.f, a2 = 0.f, a3 = 0.f;
#pragma unroll
    for (int k = 0; k < D; k += 4) {
      a0 = fmaf(yr[k + 0], wr[k + 0], a0);
      a1 = fmaf(yr[k + 1], wr[k + 1], a1);
      a2 = fmaf(yr[k + 2], wr[k + 2], a2);
      a3 = fmaf(yr[k + 3], wr[k + 3], a3);
    }
    tq[dd] = (a0 + a1) + (a2 + a3) + b2p[d];
  }
  if (act) {
    float* op = agg + (size_t)n * D + w * 16;
#pragma unroll
    for (int q = 0; q < 4; ++q)
      *reinterpret_cast<float4*>(op + 4 * q) =
          make_float4(tq[4*q], tq[4*q+1], tq[4*q+2], tq[4*q+3]);
  }
}

// ---------------- BN stats: per-feature sum / sumsq ----------------
__global__ __launch_bounds__(256) void k_stats(const float* __restrict__ t,
                                               float* __restrict__ stats) {
  int lane = threadIdx.x & 63;
  int w = threadIdx.x >> 6;
  int gw = blockIdx.x * 4 + w;
  int nw = gridDim.x * 4;
  float s = 0.f, q = 0.f;
  for (int n = gw; n < NN; n += nw) {
    float v = t[(size_t)n * D + lane];
    s += v;
    q = fmaf(v, v, q);
  }
  __shared__ float ls[8][64];
  ls[w][lane] = s;
  ls[4 + w][lane] = q;
  __syncthreads();
  if (threadIdx.x < D) {
    float S = ls[0][lane] + ls[1][lane] + ls[2][lane] + ls[3][lane];
    float Q = ls[4][lane] + ls[5][lane] + ls[6][lane] + ls[7][lane];
    unsafeAtomicAdd(&stats[lane], S);
    unsafeAtomicAdd(&stats[D + lane], Q);
  }
}

// ---------------- BN apply (+relu except last layer) ----------------
__global__ __launch_bounds__(256) void k_apply(const float* __restrict__ t,
    const float* __restrict__ stats, const float* __restrict__ gamma,
    const float* __restrict__ beta, int layer, int last, float* __restrict__ o) {
  const float inv = 1.f / (float)NN;
  int i = blockIdx.x * blockDim.x + threadIdx.x;
  int nt = gridDim.x * blockDim.x;
  for (; i < NN * D / 4; i += nt) {
    int d0 = (i & 15) * 4;
    float4 v = reinterpret_cast<const float4*>(t)[i];
    float vv[4] = {v.x, v.y, v.z, v.w};
    float r[4];
#pragma unroll
    for (int c = 0; c < 4; ++c) {
      int d = d0 + c;
      float mu = stats[d] * inv;
      float var = fmaf(-mu, mu, stats[D + d] * inv);
      float sc = gamma[layer * D + d] / sqrtf(var + BN_EPS);
      float val = fmaf(vv[c] - mu, sc, beta[layer * D + d]);
      r[c] = last ? val : fmaxf(val, 0.f);
    }
    reinterpret_cast<float4*>(o)[i] = make_float4(r[0], r[1], r[2], r[3]);
  }
}

extern "C" void kernel_launch(void* const* d_in, const int* in_sizes, int n_in,
                              void* d_out, int out_size, void* d_ws, size_t ws_size,
                              hipStream_t stream) {
  const float* x     = (const float*)d_in[0];
  const int*   ei    = (const int*)d_in[1];
  const float* ea    = (const float*)d_in[2];
  const float* atomW = (const float*)d_in[3];
  const float* atomB = (const float*)d_in[4];
  const float* eW    = (const float*)d_in[5];
  const float* eb    = (const float*)d_in[6];
  const float* W1    = (const float*)d_in[7];
  const float* b1    = (const float*)d_in[8];
  const float* W2    = (const float*)d_in[9];
  const float* b2    = (const float*)d_in[10];
  const float* eps   = (const float*)d_in[11];
  const float* gamma = (const float*)d_in[12];
  const float* beta  = (const float*)d_in[13];
  float* out = (float*)d_out;

  char* ws = (char*)d_ws;
  float* h      = (float*)ws;                                // NN*D
  float* agg    = h + (size_t)NN * D;                        // NN*D (agg, then t)
  float* stats  = agg + (size_t)NN * D;                      // 2*D (adjacent)
  float* atomWt = stats + 2 * D;                             // D*XD
  float* W1t    = atomWt + D * XD;                           // NL*D*D
  float* W2t    = W1t + NL * D * D;                          // NL*D*D
  int*   deg    = (int*)(W2t + NL * D * D);                  // NN
  int*   lps    = deg + NN;                                  // NN
  int*   rowptr = lps + NN;                                  // NN+1
  int*   cursor = rowptr + NN + 1;                           // NN
  int*   bsum   = cursor + NN;                               // 256
  int*   bpre   = bsum + 256;                                // 256
  int*   esrc   = bpre + 256;                                // NE
  int*   eidl   = esrc + NE;                                 // NE
  int*   dstp   = eidl + NE;                                 // NE
  // total ws use ~= 36.5 MB

  // weights + atom encoder
  k_prep<<<64, 256, 0, stream>>>(atomW, W1, W2, atomWt, W1t, W2t);
  k_atom<<<(NN + 255) / 256, 256, 0, stream>>>(x, atomWt, atomB, h);

  // CSR build (dst-sorted edge order)
  hipMemsetAsync(deg, 0, (size_t)NN * 4, stream);
  k_deg<<<(NE + 255) / 256, 256, 0, stream>>>(ei, deg);
  k_scan_a<<<NBLK, 256, 0, stream>>>(deg, lps, bsum);
  k_scan_b<<<1, 256, 0, stream>>>(bsum, bpre);
  k_fill<<<NBLK, 256, 0, stream>>>(lps, bpre, rowptr, cursor);
  k_scatter<<<(NE + 255) / 256, 256, 0, stream>>>(ei, cursor, esrc, eidl, dstp);

  for (int l = 0; l < NL; ++l) {
    hipMemsetAsync(agg, 0, ((size_t)NN * D + 2 * D) * 4, stream);  // agg + stats
    k_edge<<<NE / TILE_E, 256, 0, stream>>>(h, ea, eW, eb, esrc, eidl, dstp, l, agg);
    k_mlp<<<MLPB, 256, 0, stream>>>(h, W1t, b1, W2t, b2, eps, l, agg);
    k_stats<<<512, 256, 0, stream>>>(agg, stats);
    float* ho = (l == NL - 1) ? out : h;
    k_apply<<<1024, 256, 0, stream>>>(agg, stats, gamma, beta, l, (l == NL - 1) ? 1 : 0, ho);
  }
}